// Round 9
// baseline (2624.254 us; speedup 1.0000x reference)
//
#include <hip/hip_runtime.h>

typedef unsigned int u32;
typedef unsigned short u16;
typedef unsigned char u8;
typedef long long i64;
typedef __attribute__((ext_vector_type(4))) float f32x4;

#define CBSZ 8192
#define DIMV 512
#define MROWS 32768   // 8*4096
#define CAP 80        // k3 LDS candidate cap (E[cnt]~20 at DELTA=0.30 incl burst)
#define CAPO 16       // compacted per-row candidates shipped to k4 (E~1-3)
#define DELTA 0.30f   // fp8 prefilter slack during the scan
#define MARGIN 0.27f  // final filter vs global fp8 max (2x5sigma + bf16 store err)
#define NBLK4 (MROWS / 4)   // 8192 k4 blocks -> loss partials

__device__ __forceinline__ u16 f2bf(float f) {
    u32 u = __float_as_uint(f);
    u32 r = (u + 0x7fffu + ((u >> 16) & 1u)) >> 16;   // RNE
    return (u16)r;
}

__device__ __forceinline__ float wave_sum(float v) {
#pragma unroll
    for (int m = 1; m < 64; m <<= 1) v += __shfl_xor(v, m);
    return v;
}

// monotone float <-> sortable u32
__device__ __forceinline__ u32 enc_f(float f) {
    u32 u = __float_as_uint(f);
    return (u & 0x80000000u) ? ~u : (u | 0x80000000u);
}
__device__ __forceinline__ float dec_f(u32 e) {
    return (e & 0x80000000u) ? __uint_as_float(e & 0x7FFFFFFFu) : __uint_as_float(~e);
}

// async global->LDS, 16B per lane; LDS dest = wave-uniform base + lane*16
__device__ __forceinline__ void gl_lds16(const u8* g, u8* l) {
    __builtin_amdgcn_global_load_lds(
        (const __attribute__((address_space(1))) u32*)g,
        (__attribute__((address_space(3))) u32*)l, 16, 0, 0);
}

// pack 8 f32 -> 8 fp8 e4m3 (2 u32 words) via HW cvt (RNE, OCP on gfx950)
__device__ __forceinline__ uint2 pk_fp8x8(float4 v0, float4 v1) {
    u32 w0 = 0, w1 = 0;
    w0 = __builtin_amdgcn_cvt_pk_fp8_f32(v0.x, v0.y, w0, false);
    w0 = __builtin_amdgcn_cvt_pk_fp8_f32(v0.z, v0.w, w0, true);
    w1 = __builtin_amdgcn_cvt_pk_fp8_f32(v1.x, v1.y, w1, false);
    w1 = __builtin_amdgcn_cvt_pk_fp8_f32(v1.z, v1.w, w1, true);
    return make_uint2(w0, w1);
}

// K0: cast x (f32) -> xb (fp8 e4m3) in 16x16x32 fragment-linear order.
// frag f = R*16 + S (R=row-tile/16, S=k-frag/32); lane L holds row R*16+(L&15),
// k S*32+(L>>4)*8 .. +8, stored as 8B at xb + f*512 + L*8 (bytes).
__global__ __launch_bounds__(256) void k0_castx(const float* __restrict__ x,
                                                u8* __restrict__ xb) {
    int t = blockIdx.x * 256 + threadIdx.x;   // 0 .. 2,097,151
    int f = t >> 6;
    int L = t & 63;
    int R = f >> 4, S = f & 15;
    int row = R * 16 + (L & 15);
    int k = S * 32 + (L >> 4) * 8;
    const float* gp = x + (size_t)row * DIMV + k;
    float4 v0 = *(const float4*)gp, v1 = *(const float4*)(gp + 4);
    *(uint2*)(xb + (size_t)f * 512 + L * 8) = pk_fp8x8(v0, v1);
}

// K1: implicit_cb[c][d] = sum_k cb[c][k] * W[d][k]   (fp32 GEMM, 64x64 tiles)
__global__ __launch_bounds__(256) void k1_implicit(const float* __restrict__ cb,
                                                   const float* __restrict__ W,
                                                   float* __restrict__ outp) {
    __shared__ float As[64 * 64];
    __shared__ float Bs[64 * 64];
    const int c0 = blockIdx.x * 64, d0 = blockIdx.y * 64;
    const int tid = threadIdx.x;
    const int tx = tid & 15, ty = tid >> 4;
    float acc[4][4] = {};
    for (int k0 = 0; k0 < DIMV; k0 += 64) {
        __syncthreads();
#pragma unroll
        for (int it = 0; it < 4; ++it) {
            int chunk = tid + 256 * it;
            int row = chunk >> 4;
            int g = chunk & 15;
            int gs = (g ^ (row & 15)) * 4;
            *(float4*)&As[row * 64 + gs] =
                *(const float4*)(cb + (size_t)(c0 + row) * DIMV + k0 + g * 4);
            *(float4*)&Bs[row * 64 + gs] =
                *(const float4*)(W + (size_t)(d0 + row) * DIMV + k0 + g * 4);
        }
        __syncthreads();
#pragma unroll
        for (int k = 0; k < 64; k += 4) {
            const int g = k >> 2;
            float4 a[4], b[4];
#pragma unroll
            for (int i = 0; i < 4; ++i) a[i] = *(float4*)&As[(ty + 16 * i) * 64 + ((g ^ ty) * 4)];
#pragma unroll
            for (int j = 0; j < 4; ++j) b[j] = *(float4*)&Bs[(tx + 16 * j) * 64 + ((g ^ tx) * 4)];
#pragma unroll
            for (int i = 0; i < 4; ++i)
#pragma unroll
                for (int j = 0; j < 4; ++j) {
                    acc[i][j] = fmaf(a[i].x, b[j].x, acc[i][j]);
                    acc[i][j] = fmaf(a[i].y, b[j].y, acc[i][j]);
                    acc[i][j] = fmaf(a[i].z, b[j].z, acc[i][j]);
                    acc[i][j] = fmaf(a[i].w, b[j].w, acc[i][j]);
                }
        }
    }
#pragma unroll
    for (int i = 0; i < 4; ++i)
#pragma unroll
        for (int j = 0; j < 4; ++j)
            outp[(size_t)(c0 + ty + 16 * i) * DIMV + d0 + tx + 16 * j] = acc[i][j];
}

// K2: in-place row l2norm of cbn + fp8 codebook in wave-major STREAM order.
// Tile t = c>>4 (16 codes); t -> wave region wq=t>>6, r=t&63, ct=r>>2, u=r&3.
// Stream frag f = ((wq*16 + ct)*16 + kf)*4 + u (kf = dim k-frag 0..15); each
// wave's k3 stream is one contiguous 512KB region; chunk (ct,kf) = 2KB of
// 4 tile-frags at imm offsets 0/512/1024/1536 bytes.
__global__ __launch_bounds__(256) void k2_normrows(float* __restrict__ cbn,
                                                   u8* __restrict__ cbb) {
    const int row = blockIdx.x * 4 + (threadIdx.x >> 6);
    const int lane = threadIdx.x & 63;
    float* p = cbn + (size_t)row * DIMV + lane * 8;
    float4 v0 = *(float4*)p, v1 = *(float4*)(p + 4);
    float ss = v0.x * v0.x + v0.y * v0.y + v0.z * v0.z + v0.w * v0.w
             + v1.x * v1.x + v1.y * v1.y + v1.z * v1.z + v1.w * v1.w;
    ss = wave_sum(ss);
    float n = fmaxf(sqrtf(ss), 1e-12f);
    v0.x /= n; v0.y /= n; v0.z /= n; v0.w /= n;
    v1.x /= n; v1.y /= n; v1.z /= n; v1.w /= n;
    *(float4*)p = v0;
    *(float4*)(p + 4) = v1;
    // fragment position: lane covers dims lane*8..+7 -> kf=lane>>2, j=lane&3;
    // lane-slot Ls = j*16 + (code&15)
    int t = row >> 4;
    int wq = t >> 6, r = t & 63, ct = r >> 2, u = r & 3;
    int kf = lane >> 2;
    int f = ((wq * 16 + ct) * 16 + kf) * 4 + u;
    int Ls = (lane & 3) * 16 + (row & 15);
    *(uint2*)(cbb + (size_t)f * 512 + Ls * 8) = pk_fp8x8(v0, v1);
}

// K3: barrier-free fp8 16x16x32-MFMA prefilter, 64-row blocks.
// Grid 512 blocks x 512 thr (8 waves), ~53 KB LDS, ~124 unified regs ->
// 2 blocks/CU, 4 waves/SIMD. Candidates stored in LDS as (code<<16)|bf16score.
// NEW: compaction epilogue — after the final barrier pmax[rl] is the row's
// GLOBAL fp8 max (block covers all 8192 codes), so wave 0 filters candidates
// to score >= pmax - MARGIN and ships only ~1-3 codes/row to k4 (CAPO=16).
// Any code that could win the fp64 rescore survives: fp8 2x5sigma + bf16
// store rounding < MARGIN < DELTA. Overflow/empty -> sentinel -> k4 fallback.
// Swapped MFMA operands: D col = x-row (lane&15), row-of-D = code ->
// per-row code-max is lane-local (15-op fmax tree) + 2 shfls.
__global__ __launch_bounds__(512, 4) void k3_scan(const u8* __restrict__ xb,
                                                  const u8* __restrict__ cbb,
                                                  u16* __restrict__ cand_g,
                                                  u32* __restrict__ cnt_g) {
    __shared__ __align__(16) u8 xs[64 * 512];   // 32 KB: frag m = rt*16+kf at m*512B
    __shared__ u32 pmax[64];
    __shared__ u32 cnt[64];
    __shared__ u32 cand[64 * CAP];              // 20.5 KB: (code<<16)|bf16(score)

    const int tid = threadIdx.x;
    const int lane = tid & 63;
    const int w = tid >> 6;           // wave 0..7
    const int r0 = blockIdx.x * 64;

    if (tid < 64) { pmax[tid] = 0x007FFFFFu; cnt[tid] = 0; }   // enc(-inf), 0
    // stage xs once: 64 frags of 512B; wave w stages frags w*8..w*8+7
#pragma unroll
    for (int i = 0; i < 4; ++i) {
        size_t off = (size_t)blockIdx.x * 32768 + w * 4096 + i * 1024;
        gl_lds16(xb + off + lane * 16, &xs[w * 4096 + i * 1024]);
    }
    // wave's linear code stream: 256 chunks x 2048 B; prime ring slots 0..3
    const u8* stream = cbb + (size_t)w * 524288 + lane * 8;
    i64 B[4][4];   // [ring slot][code tile], 2 VGPR each
#pragma unroll
    for (int s = 0; s < 4; ++s)
#pragma unroll
        for (int u = 0; u < 4; ++u)
            B[s][u] = *(const i64*)(stream + s * 2048 + u * 512);
    const u8* cur = stream + 4 * 2048;   // next chunk to fetch (q=4)
    __syncthreads();   // drains vmcnt: xs + ring prime; publishes pmax/cnt

    const int myrow_lo = lane & 15;   // this lane's row (low part)
    const int cgrp = lane >> 4;       // code sub-group 0..3

    for (int ct = 0; ct < 16; ++ct) {
        f32x4 acc[4][4] = {};                 // [row-tile][code-tile]
#pragma unroll
        for (int kf = 0; kf < 16; ++kf) {
            const int s = kf & 3;             // static: loop fully unrolled
            i64 a0 = *(const i64*)&xs[(0 * 16 + kf) * 512 + lane * 8];
            i64 a1 = *(const i64*)&xs[(1 * 16 + kf) * 512 + lane * 8];
            i64 a2 = *(const i64*)&xs[(2 * 16 + kf) * 512 + lane * 8];
            i64 a3 = *(const i64*)&xs[(3 * 16 + kf) * 512 + lane * 8];
            acc[0][0] = __builtin_amdgcn_mfma_f32_16x16x32_fp8_fp8(B[s][0], a0, acc[0][0], 0, 0, 0);
            acc[0][1] = __builtin_amdgcn_mfma_f32_16x16x32_fp8_fp8(B[s][1], a0, acc[0][1], 0, 0, 0);
            acc[0][2] = __builtin_amdgcn_mfma_f32_16x16x32_fp8_fp8(B[s][2], a0, acc[0][2], 0, 0, 0);
            acc[0][3] = __builtin_amdgcn_mfma_f32_16x16x32_fp8_fp8(B[s][3], a0, acc[0][3], 0, 0, 0);
            acc[1][0] = __builtin_amdgcn_mfma_f32_16x16x32_fp8_fp8(B[s][0], a1, acc[1][0], 0, 0, 0);
            acc[1][1] = __builtin_amdgcn_mfma_f32_16x16x32_fp8_fp8(B[s][1], a1, acc[1][1], 0, 0, 0);
            acc[1][2] = __builtin_amdgcn_mfma_f32_16x16x32_fp8_fp8(B[s][2], a1, acc[1][2], 0, 0, 0);
            acc[1][3] = __builtin_amdgcn_mfma_f32_16x16x32_fp8_fp8(B[s][3], a1, acc[1][3], 0, 0, 0);
            acc[2][0] = __builtin_amdgcn_mfma_f32_16x16x32_fp8_fp8(B[s][0], a2, acc[2][0], 0, 0, 0);
            acc[2][1] = __builtin_amdgcn_mfma_f32_16x16x32_fp8_fp8(B[s][1], a2, acc[2][1], 0, 0, 0);
            acc[2][2] = __builtin_amdgcn_mfma_f32_16x16x32_fp8_fp8(B[s][2], a2, acc[2][2], 0, 0, 0);
            acc[2][3] = __builtin_amdgcn_mfma_f32_16x16x32_fp8_fp8(B[s][3], a2, acc[2][3], 0, 0, 0);
            acc[3][0] = __builtin_amdgcn_mfma_f32_16x16x32_fp8_fp8(B[s][0], a3, acc[3][0], 0, 0, 0);
            acc[3][1] = __builtin_amdgcn_mfma_f32_16x16x32_fp8_fp8(B[s][1], a3, acc[3][1], 0, 0, 0);
            acc[3][2] = __builtin_amdgcn_mfma_f32_16x16x32_fp8_fp8(B[s][2], a3, acc[3][2], 0, 0, 0);
            acc[3][3] = __builtin_amdgcn_mfma_f32_16x16x32_fp8_fp8(B[s][3], a3, acc[3][3], 0, 0, 0);
            // refill slot s with chunk q+4 (q = ct*16+kf). Tail overruns the
            // wave's region by <=8KB into cand_g scratch: allocated, values
            // never consumed -> benign.
            B[s][0] = *(const i64*)(cur + 0 * 512);
            B[s][1] = *(const i64*)(cur + 1 * 512);
            B[s][2] = *(const i64*)(cur + 2 * 512);
            B[s][3] = *(const i64*)(cur + 3 * 512);
            cur += 2048;
        }
        // candidate phase (no barriers; stale pmax reads only over-push).
        // Ring keeps the next ct's chunks in flight underneath this.
#pragma unroll
        for (int rt = 0; rt < 4; ++rt) {
            const int rl = rt * 16 + myrow_lo;
            // lane-local max over this lane's 16 codes for row rl
            float mu0 = fmaxf(fmaxf(acc[rt][0][0], acc[rt][0][1]),
                              fmaxf(acc[rt][0][2], acc[rt][0][3]));
            float mu1 = fmaxf(fmaxf(acc[rt][1][0], acc[rt][1][1]),
                              fmaxf(acc[rt][1][2], acc[rt][1][3]));
            float mu2 = fmaxf(fmaxf(acc[rt][2][0], acc[rt][2][1]),
                              fmaxf(acc[rt][2][2], acc[rt][2][3]));
            float mu3 = fmaxf(fmaxf(acc[rt][3][0], acc[rt][3][1]),
                              fmaxf(acc[rt][3][2], acc[rt][3][3]));
            float mloc = fmaxf(fmaxf(mu0, mu1), fmaxf(mu2, mu3));
            // wave-ct row max: reduce across the 4 code sub-groups
            float m = fmaxf(mloc, __shfl_xor(mloc, 16));
            m = fmaxf(m, __shfl_xor(m, 32));
            u32 pme = pmax[rl];
            float pv = dec_f(pme);
            if (m > pv && cgrp == 0) atomicMax(&pmax[rl], enc_f(m));
            float thr = fmaxf(pv, m) - DELTA;
            if (mloc >= thr) {       // rare: exec-masked enumeration
#pragma unroll
                for (int u = 0; u < 4; ++u)
#pragma unroll
                    for (int r = 0; r < 4; ++r) {
                        if (acc[rt][u][r] >= thr) {
                            u32 p = atomicAdd(&cnt[rl], 1u);
                            if (p < CAP) {
                                int code = (w * 64 + ct * 4 + u) * 16 + cgrp * 4 + r;
                                cand[rl * CAP + p] =
                                    ((u32)code << 16) | f2bf(acc[rt][u][r]);
                            }
                        }
                    }
            }
        }
    }
    __syncthreads();   // pmax/cand final: block scanned ALL codes
    if (tid < 64) {
        u32 n = cnt[tid];
        float t2 = dec_f(pmax[tid]) - MARGIN;
        u32 k = 0;
        if (n <= CAP) {
            for (u32 i = 0; i < n; ++i) {
                u32 e = cand[tid * CAP + i];
                float sc = __uint_as_float((e & 0xFFFFu) << 16);
                if (sc >= t2) {
                    if (k < CAPO) cand_g[(size_t)(r0 + tid) * CAPO + k] = (u16)(e >> 16);
                    ++k;
                }
            }
        }
        cnt_g[r0 + tid] = (n > CAP || k == 0 || k > CAPO) ? 0xFFFFFFFFu : k;
    }
}

// K4: fp64 rescore of the ~1-3 prefiltered candidates + rotation trick +
// per-block loss partial (NO global atomics). One wave per row, 4 rows/block.
// Rotation uses the exact structure of this problem: src = x/||x||, tgt =
// normalized codebook row -> norm_s = norm_t = 1, u = s, q = t, eu = 1,
// scale = 1 (f32 deviations ~1e-7 << tolerance). Chains: ss, then {w2, e.wv}
// interleaved -> 2 serial reduction times instead of 6.
__global__ __launch_bounds__(256) void k4_rotate(const float* __restrict__ x,
                                                 const float* __restrict__ cbn,
                                                 const u16* __restrict__ cand_g,
                                                 const u32* __restrict__ cnt_g,
                                                 float* __restrict__ outq,
                                                 float* __restrict__ out_idx,
                                                 float* __restrict__ lossb) {
    __shared__ float xsh[4 * 512];   // per-wave fallback scratch
    __shared__ float lsum[4];
    const int row = blockIdx.x * 4 + (threadIdx.x >> 6);
    const int w = threadIdx.x >> 6;
    const int lane = threadIdx.x & 63;
    const float* xp = x + (size_t)row * DIMV + lane * 8;
    float4 a0 = *(const float4*)xp, a1 = *(const float4*)(xp + 4);
    double xd[8] = {a0.x, a0.y, a0.z, a0.w, a1.x, a1.y, a1.z, a1.w};

    u32 nc = cnt_g[row];
    double best = -1e300;
    int bi = CBSZ;
    if (nc != 0xFFFFFFFFu) {
        for (u32 i = 0; i < nc; ++i) {      // nc ~ 1-3 after k3's filter
            int c = cand_g[(size_t)row * CAPO + i];
            const float* cp = cbn + (size_t)c * DIMV + lane * 8;
            float4 c0 = *(const float4*)cp, c1 = *(const float4*)(cp + 4);
            double d = xd[0] * c0.x + xd[1] * c0.y + xd[2] * c0.z + xd[3] * c0.w
                     + xd[4] * c1.x + xd[5] * c1.y + xd[6] * c1.z + xd[7] * c1.w;
#pragma unroll
            for (int m = 1; m < 64; m <<= 1) d += __shfl_xor(d, m);
            if (d > best || (d == best && c < bi)) { best = d; bi = c; }
        }
    } else {
        // exact parallel fallback (cnt/compact overflow; statistically never)
        *(float4*)&xsh[w * 512 + lane * 8] = a0;
        *(float4*)&xsh[w * 512 + lane * 8 + 4] = a1;
        float bf = -1e30f;
        for (int c = lane; c < CBSZ; c += 64) {
            const float* cp = cbn + (size_t)c * DIMV;
            float d = 0.f;
            for (int k = 0; k < DIMV; k += 4) {
                d = fmaf(cp[k],     xsh[w * 512 + k],     d);
                d = fmaf(cp[k + 1], xsh[w * 512 + k + 1], d);
                d = fmaf(cp[k + 2], xsh[w * 512 + k + 2], d);
                d = fmaf(cp[k + 3], xsh[w * 512 + k + 3], d);
            }
            bf = fmaxf(bf, d);
        }
        float M = bf;
#pragma unroll
        for (int m = 1; m < 64; m <<= 1) M = fmaxf(M, __shfl_xor(M, m));
        double bd = -1e300;
        int bc = CBSZ;
        for (int c = lane; c < CBSZ; c += 64) {
            const float* cp = cbn + (size_t)c * DIMV;
            float d = 0.f;
            for (int k = 0; k < DIMV; k += 4) {
                d = fmaf(cp[k],     xsh[w * 512 + k],     d);
                d = fmaf(cp[k + 1], xsh[w * 512 + k + 1], d);
                d = fmaf(cp[k + 2], xsh[w * 512 + k + 2], d);
                d = fmaf(cp[k + 3], xsh[w * 512 + k + 3], d);
            }
            if (d >= M - 0.1f) {
                double dd = 0.0;
                for (int k = 0; k < DIMV; ++k)
                    dd += (double)cp[k] * (double)xsh[w * 512 + k];
                if (dd > bd || (dd == bd && c < bc)) { bd = dd; bc = c; }
            }
        }
#pragma unroll
        for (int m = 1; m < 64; m <<= 1) {
            double ov = __shfl_xor(bd, m);
            int oi = __shfl_xor(bc, m);
            if (ov > bd || (ov == bd && oi < bc)) { bd = ov; bc = oi; }
        }
        bi = bc;
    }
    int ci = bi < 0 ? 0 : (bi > CBSZ - 1 ? CBSZ - 1 : bi);

    // --- rotation trick (simplified: unit s, unit t, eu=1, scale=1) ---
    float xf[8] = {a0.x, a0.y, a0.z, a0.w, a1.x, a1.y, a1.z, a1.w};
    float ss = 0.f;
#pragma unroll
    for (int i = 0; i < 8; ++i) ss += xf[i] * xf[i];
    ss = wave_sum(ss);
    float nx = fmaxf(sqrtf(ss), 1e-12f);
    float s[8];
#pragma unroll
    for (int i = 0; i < 8; ++i) s[i] = xf[i] / nx;
    const float* tp = cbn + (size_t)ci * DIMV + lane * 8;
    float4 t0 = *(const float4*)tp, t1 = *(const float4*)(tp + 4);
    float t[8] = {t0.x, t0.y, t0.z, t0.w, t1.x, t1.y, t1.z, t1.w};
    float wv[8];
    float w2 = 0.f, ewr = 0.f, lacc = 0.f;
#pragma unroll
    for (int i = 0; i < 8; ++i) {
        wv[i] = s[i] + t[i];
        w2 += wv[i] * wv[i];
        ewr += s[i] * wv[i];
        float d = s[i] - t[i];
        lacc += d * d;
    }
#pragma unroll
    for (int m = 1; m < 64; m <<= 1) {    // two interleaved chains
        w2 += __shfl_xor(w2, m);
        ewr += __shfl_xor(ewr, m);
    }
    float wn = fmaxf(sqrtf(w2), 1e-12f);
    float iw = 1.f / wn;
    float coef = 2.f * ewr * iw * iw;
    float r[8];
#pragma unroll
    for (int i = 0; i < 8; ++i)
        r[i] = s[i] - coef * wv[i] + 2.f * t[i];
    float* op = outq + (size_t)row * DIMV + lane * 8;
    *(float4*)op = make_float4(r[0], r[1], r[2], r[3]);
    *(float4*)(op + 4) = make_float4(r[4], r[5], r[6], r[7]);
    lacc = wave_sum(lacc);
    if (lane == 0) {
        out_idx[row] = (float)ci;
        lsum[w] = lacc;
    }
    __syncthreads();
    if (threadIdx.x == 0)
        lossb[blockIdx.x] = lsum[0] + lsum[1] + lsum[2] + lsum[3];
}

// K5: reduce 8192 per-block partials deterministically; 1.25 * sum / (B*N*D)
__global__ __launch_bounds__(256) void k5_loss(const float* __restrict__ lossb,
                                               float* __restrict__ outl) {
    __shared__ float wsum[4];
    const int tid = threadIdx.x;
    float s = 0.f;
    for (int i = tid; i < NBLK4; i += 256) s += lossb[i];
    s = wave_sum(s);
    if ((tid & 63) == 0) wsum[tid >> 6] = s;
    __syncthreads();
    if (tid == 0)
        outl[0] = (wsum[0] + wsum[1] + wsum[2] + wsum[3]) * 1.25f / 16777216.0f;
}

extern "C" void kernel_launch(void* const* d_in, const int* in_sizes, int n_in,
                              void* d_out, int out_size, void* d_ws, size_t ws_size,
                              hipStream_t stream) {
    (void)in_sizes; (void)n_in; (void)out_size; (void)ws_size;
    const float* x  = (const float*)d_in[0];   // (8,4096,512) f32
    const float* W  = (const float*)d_in[1];   // (512,512) f32
    const float* cb = (const float*)d_in[2];   // (8192,512) f32
    float* out = (float*)d_out;
    float* out_q = out;                        // 16,777,216 f32
    float* out_i = out + 16777216;             // 32,768 f32
    float* out_l = out + 16777216 + 32768;     // 1 f32

    // xb scratch (fp8, 16MB) lives in the out_q region: written by k0, read
    // by k3, then k4 overwrites out_q with the real output.
    u8* xb = (u8*)d_out;

    float* ws = (float*)d_ws;
    float* cbn = ws;                                  // 4,194,304 f32 (16.8 MB)
    u8*    cbb = (u8*)(cbn + (size_t)CBSZ * DIMV);    // 4,194,304 u8 (4.2 MB)
    u16*   cand_g = (u16*)(cbb + (size_t)CBSZ * DIMV);     // 32768*CAPO u16 (1.0 MB)
    u32*   cnt_g = (u32*)(cand_g + (size_t)MROWS * CAPO);  // 32,768 u32
    float* lossb = (float*)(cnt_g + MROWS);                // 8192 f32

    k0_castx<<<MROWS * DIMV / 8 / 256, 256, 0, stream>>>(x, xb);
    k1_implicit<<<dim3(CBSZ / 64, DIMV / 64), 256, 0, stream>>>(cb, W, cbn);
    k2_normrows<<<CBSZ / 4, 256, 0, stream>>>(cbn, cbb);
    k3_scan<<<MROWS / 64, 512, 0, stream>>>(xb, cbb, cand_g, cnt_g);
    k4_rotate<<<MROWS / 4, 256, 0, stream>>>(x, cbn, cand_g, cnt_g, out_q, out_i, lossb);
    k5_loss<<<1, 256, 0, stream>>>(lossb, out_l);
}

// Round 10
// 433.742 us; speedup vs baseline: 6.0503x; 6.0503x over previous
//
#include <hip/hip_runtime.h>

typedef unsigned int u32;
typedef unsigned short u16;
typedef unsigned char u8;
typedef long long i64;
typedef __attribute__((ext_vector_type(4))) float f32x4;

#define CBSZ 8192
#define DIMV 512
#define MROWS 32768   // 8*4096
#define CAP 80        // k3 LDS candidate cap (n <= 80 proven on-dataset, round 8)
#define CAPO 80       // ship ALL filtered candidates: k <= n <= CAP -> no k-sentinel.
                      // Round 9 lesson: W warps the code sphere (Marchenko-Pastur
                      // singular spread) -> some rows have >16 near-max codes; the
                      // CAPO=16 sentinel sent them to the 2ms uncoalesced fallback.
#define DELTA 0.30f   // fp8 prefilter slack during the scan
#define MARGIN 0.27f  // final filter vs global fp8 max (2x5sigma + bf16 store err)
#define NBLK4 (MROWS / 4)   // 8192 k4 blocks -> loss partials

__device__ __forceinline__ u16 f2bf(float f) {
    u32 u = __float_as_uint(f);
    u32 r = (u + 0x7fffu + ((u >> 16) & 1u)) >> 16;   // RNE
    return (u16)r;
}

__device__ __forceinline__ float wave_sum(float v) {
#pragma unroll
    for (int m = 1; m < 64; m <<= 1) v += __shfl_xor(v, m);
    return v;
}

// monotone float <-> sortable u32
__device__ __forceinline__ u32 enc_f(float f) {
    u32 u = __float_as_uint(f);
    return (u & 0x80000000u) ? ~u : (u | 0x80000000u);
}
__device__ __forceinline__ float dec_f(u32 e) {
    return (e & 0x80000000u) ? __uint_as_float(e & 0x7FFFFFFFu) : __uint_as_float(~e);
}

// async global->LDS, 16B per lane; LDS dest = wave-uniform base + lane*16
__device__ __forceinline__ void gl_lds16(const u8* g, u8* l) {
    __builtin_amdgcn_global_load_lds(
        (const __attribute__((address_space(1))) u32*)g,
        (__attribute__((address_space(3))) u32*)l, 16, 0, 0);
}

// pack 8 f32 -> 8 fp8 e4m3 (2 u32 words) via HW cvt (RNE, OCP on gfx950)
__device__ __forceinline__ uint2 pk_fp8x8(float4 v0, float4 v1) {
    u32 w0 = 0, w1 = 0;
    w0 = __builtin_amdgcn_cvt_pk_fp8_f32(v0.x, v0.y, w0, false);
    w0 = __builtin_amdgcn_cvt_pk_fp8_f32(v0.z, v0.w, w0, true);
    w1 = __builtin_amdgcn_cvt_pk_fp8_f32(v1.x, v1.y, w1, false);
    w1 = __builtin_amdgcn_cvt_pk_fp8_f32(v1.z, v1.w, w1, true);
    return make_uint2(w0, w1);
}

// K0: cast x (f32) -> xb (fp8 e4m3) in 16x16x32 fragment-linear order.
// frag f = R*16 + S (R=row-tile/16, S=k-frag/32); lane L holds row R*16+(L&15),
// k S*32+(L>>4)*8 .. +8, stored as 8B at xb + f*512 + L*8 (bytes).
__global__ __launch_bounds__(256) void k0_castx(const float* __restrict__ x,
                                                u8* __restrict__ xb) {
    int t = blockIdx.x * 256 + threadIdx.x;   // 0 .. 2,097,151
    int f = t >> 6;
    int L = t & 63;
    int R = f >> 4, S = f & 15;
    int row = R * 16 + (L & 15);
    int k = S * 32 + (L >> 4) * 8;
    const float* gp = x + (size_t)row * DIMV + k;
    float4 v0 = *(const float4*)gp, v1 = *(const float4*)(gp + 4);
    *(uint2*)(xb + (size_t)f * 512 + L * 8) = pk_fp8x8(v0, v1);
}

// K1: implicit_cb[c][d] = sum_k cb[c][k] * W[d][k]   (fp32 GEMM, 64x64 tiles)
__global__ __launch_bounds__(256) void k1_implicit(const float* __restrict__ cb,
                                                   const float* __restrict__ W,
                                                   float* __restrict__ outp) {
    __shared__ float As[64 * 64];
    __shared__ float Bs[64 * 64];
    const int c0 = blockIdx.x * 64, d0 = blockIdx.y * 64;
    const int tid = threadIdx.x;
    const int tx = tid & 15, ty = tid >> 4;
    float acc[4][4] = {};
    for (int k0 = 0; k0 < DIMV; k0 += 64) {
        __syncthreads();
#pragma unroll
        for (int it = 0; it < 4; ++it) {
            int chunk = tid + 256 * it;
            int row = chunk >> 4;
            int g = chunk & 15;
            int gs = (g ^ (row & 15)) * 4;
            *(float4*)&As[row * 64 + gs] =
                *(const float4*)(cb + (size_t)(c0 + row) * DIMV + k0 + g * 4);
            *(float4*)&Bs[row * 64 + gs] =
                *(const float4*)(W + (size_t)(d0 + row) * DIMV + k0 + g * 4);
        }
        __syncthreads();
#pragma unroll
        for (int k = 0; k < 64; k += 4) {
            const int g = k >> 2;
            float4 a[4], b[4];
#pragma unroll
            for (int i = 0; i < 4; ++i) a[i] = *(float4*)&As[(ty + 16 * i) * 64 + ((g ^ ty) * 4)];
#pragma unroll
            for (int j = 0; j < 4; ++j) b[j] = *(float4*)&Bs[(tx + 16 * j) * 64 + ((g ^ tx) * 4)];
#pragma unroll
            for (int i = 0; i < 4; ++i)
#pragma unroll
                for (int j = 0; j < 4; ++j) {
                    acc[i][j] = fmaf(a[i].x, b[j].x, acc[i][j]);
                    acc[i][j] = fmaf(a[i].y, b[j].y, acc[i][j]);
                    acc[i][j] = fmaf(a[i].z, b[j].z, acc[i][j]);
                    acc[i][j] = fmaf(a[i].w, b[j].w, acc[i][j]);
                }
        }
    }
#pragma unroll
    for (int i = 0; i < 4; ++i)
#pragma unroll
        for (int j = 0; j < 4; ++j)
            outp[(size_t)(c0 + ty + 16 * i) * DIMV + d0 + tx + 16 * j] = acc[i][j];
}

// K2: in-place row l2norm of cbn + fp8 codebook in wave-major STREAM order.
// Tile t = c>>4 (16 codes); t -> wave region wq=t>>6, r=t&63, ct=r>>2, u=r&3.
// Stream frag f = ((wq*16 + ct)*16 + kf)*4 + u (kf = dim k-frag 0..15); each
// wave's k3 stream is one contiguous 512KB region; chunk (ct,kf) = 2KB of
// 4 tile-frags at imm offsets 0/512/1024/1536 bytes.
__global__ __launch_bounds__(256) void k2_normrows(float* __restrict__ cbn,
                                                   u8* __restrict__ cbb) {
    const int row = blockIdx.x * 4 + (threadIdx.x >> 6);
    const int lane = threadIdx.x & 63;
    float* p = cbn + (size_t)row * DIMV + lane * 8;
    float4 v0 = *(float4*)p, v1 = *(float4*)(p + 4);
    float ss = v0.x * v0.x + v0.y * v0.y + v0.z * v0.z + v0.w * v0.w
             + v1.x * v1.x + v1.y * v1.y + v1.z * v1.z + v1.w * v1.w;
    ss = wave_sum(ss);
    float n = fmaxf(sqrtf(ss), 1e-12f);
    v0.x /= n; v0.y /= n; v0.z /= n; v0.w /= n;
    v1.x /= n; v1.y /= n; v1.z /= n; v1.w /= n;
    *(float4*)p = v0;
    *(float4*)(p + 4) = v1;
    // fragment position: lane covers dims lane*8..+7 -> kf=lane>>2, j=lane&3;
    // lane-slot Ls = j*16 + (code&15)
    int t = row >> 4;
    int wq = t >> 6, r = t & 63, ct = r >> 2, u = r & 3;
    int kf = lane >> 2;
    int f = ((wq * 16 + ct) * 16 + kf) * 4 + u;
    int Ls = (lane & 3) * 16 + (row & 15);
    *(uint2*)(cbb + (size_t)f * 512 + Ls * 8) = pk_fp8x8(v0, v1);
}

// K3: barrier-free fp8 16x16x32-MFMA prefilter, 64-row blocks.
// Grid 512 blocks x 512 thr (8 waves), ~53 KB LDS, ~124 unified regs ->
// 2 blocks/CU, 4 waves/SIMD. Candidates stored in LDS as (code<<16)|bf16score.
// Compaction epilogue: after the final barrier pmax[rl] is the row's GLOBAL
// fp8 max (block covers all 8192 codes); thread tid filters candidates to
// score >= pmax - MARGIN. With CAPO == CAP every filtered candidate ships,
// so the sentinel only fires for n > CAP or k == 0 — both proven-never on
// this dataset (round 8/9). Any code that could win the fp64 rescore
// survives the filter: fp8 2x5sigma + bf16 store rounding < MARGIN < DELTA.
// Swapped MFMA operands: D col = x-row (lane&15), row-of-D = code ->
// per-row code-max is lane-local (15-op fmax tree) + 2 shfls.
__global__ __launch_bounds__(512, 4) void k3_scan(const u8* __restrict__ xb,
                                                  const u8* __restrict__ cbb,
                                                  u16* __restrict__ cand_g,
                                                  u32* __restrict__ cnt_g) {
    __shared__ __align__(16) u8 xs[64 * 512];   // 32 KB: frag m = rt*16+kf at m*512B
    __shared__ u32 pmax[64];
    __shared__ u32 cnt[64];
    __shared__ u32 cand[64 * CAP];              // 20.5 KB: (code<<16)|bf16(score)

    const int tid = threadIdx.x;
    const int lane = tid & 63;
    const int w = tid >> 6;           // wave 0..7
    const int r0 = blockIdx.x * 64;

    if (tid < 64) { pmax[tid] = 0x007FFFFFu; cnt[tid] = 0; }   // enc(-inf), 0
    // stage xs once: 64 frags of 512B; wave w stages frags w*8..w*8+7
#pragma unroll
    for (int i = 0; i < 4; ++i) {
        size_t off = (size_t)blockIdx.x * 32768 + w * 4096 + i * 1024;
        gl_lds16(xb + off + lane * 16, &xs[w * 4096 + i * 1024]);
    }
    // wave's linear code stream: 256 chunks x 2048 B; prime ring slots 0..3
    const u8* stream = cbb + (size_t)w * 524288 + lane * 8;
    i64 B[4][4];   // [ring slot][code tile], 2 VGPR each
#pragma unroll
    for (int s = 0; s < 4; ++s)
#pragma unroll
        for (int u = 0; u < 4; ++u)
            B[s][u] = *(const i64*)(stream + s * 2048 + u * 512);
    const u8* cur = stream + 4 * 2048;   // next chunk to fetch (q=4)
    __syncthreads();   // drains vmcnt: xs + ring prime; publishes pmax/cnt

    const int myrow_lo = lane & 15;   // this lane's row (low part)
    const int cgrp = lane >> 4;       // code sub-group 0..3

    for (int ct = 0; ct < 16; ++ct) {
        f32x4 acc[4][4] = {};                 // [row-tile][code-tile]
#pragma unroll
        for (int kf = 0; kf < 16; ++kf) {
            const int s = kf & 3;             // static: loop fully unrolled
            i64 a0 = *(const i64*)&xs[(0 * 16 + kf) * 512 + lane * 8];
            i64 a1 = *(const i64*)&xs[(1 * 16 + kf) * 512 + lane * 8];
            i64 a2 = *(const i64*)&xs[(2 * 16 + kf) * 512 + lane * 8];
            i64 a3 = *(const i64*)&xs[(3 * 16 + kf) * 512 + lane * 8];
            acc[0][0] = __builtin_amdgcn_mfma_f32_16x16x32_fp8_fp8(B[s][0], a0, acc[0][0], 0, 0, 0);
            acc[0][1] = __builtin_amdgcn_mfma_f32_16x16x32_fp8_fp8(B[s][1], a0, acc[0][1], 0, 0, 0);
            acc[0][2] = __builtin_amdgcn_mfma_f32_16x16x32_fp8_fp8(B[s][2], a0, acc[0][2], 0, 0, 0);
            acc[0][3] = __builtin_amdgcn_mfma_f32_16x16x32_fp8_fp8(B[s][3], a0, acc[0][3], 0, 0, 0);
            acc[1][0] = __builtin_amdgcn_mfma_f32_16x16x32_fp8_fp8(B[s][0], a1, acc[1][0], 0, 0, 0);
            acc[1][1] = __builtin_amdgcn_mfma_f32_16x16x32_fp8_fp8(B[s][1], a1, acc[1][1], 0, 0, 0);
            acc[1][2] = __builtin_amdgcn_mfma_f32_16x16x32_fp8_fp8(B[s][2], a1, acc[1][2], 0, 0, 0);
            acc[1][3] = __builtin_amdgcn_mfma_f32_16x16x32_fp8_fp8(B[s][3], a1, acc[1][3], 0, 0, 0);
            acc[2][0] = __builtin_amdgcn_mfma_f32_16x16x32_fp8_fp8(B[s][0], a2, acc[2][0], 0, 0, 0);
            acc[2][1] = __builtin_amdgcn_mfma_f32_16x16x32_fp8_fp8(B[s][1], a2, acc[2][1], 0, 0, 0);
            acc[2][2] = __builtin_amdgcn_mfma_f32_16x16x32_fp8_fp8(B[s][2], a2, acc[2][2], 0, 0, 0);
            acc[2][3] = __builtin_amdgcn_mfma_f32_16x16x32_fp8_fp8(B[s][3], a2, acc[2][3], 0, 0, 0);
            acc[3][0] = __builtin_amdgcn_mfma_f32_16x16x32_fp8_fp8(B[s][0], a3, acc[3][0], 0, 0, 0);
            acc[3][1] = __builtin_amdgcn_mfma_f32_16x16x32_fp8_fp8(B[s][1], a3, acc[3][1], 0, 0, 0);
            acc[3][2] = __builtin_amdgcn_mfma_f32_16x16x32_fp8_fp8(B[s][2], a3, acc[3][2], 0, 0, 0);
            acc[3][3] = __builtin_amdgcn_mfma_f32_16x16x32_fp8_fp8(B[s][3], a3, acc[3][3], 0, 0, 0);
            // refill slot s with chunk q+4 (q = ct*16+kf). Tail overruns the
            // wave's region by <=8KB into the next region / cand_g scratch:
            // reads only, values never consumed -> benign.
            B[s][0] = *(const i64*)(cur + 0 * 512);
            B[s][1] = *(const i64*)(cur + 1 * 512);
            B[s][2] = *(const i64*)(cur + 2 * 512);
            B[s][3] = *(const i64*)(cur + 3 * 512);
            cur += 2048;
        }
        // candidate phase (no barriers; stale pmax reads only over-push).
        // Ring keeps the next ct's chunks in flight underneath this.
#pragma unroll
        for (int rt = 0; rt < 4; ++rt) {
            const int rl = rt * 16 + myrow_lo;
            // lane-local max over this lane's 16 codes for row rl
            float mu0 = fmaxf(fmaxf(acc[rt][0][0], acc[rt][0][1]),
                              fmaxf(acc[rt][0][2], acc[rt][0][3]));
            float mu1 = fmaxf(fmaxf(acc[rt][1][0], acc[rt][1][1]),
                              fmaxf(acc[rt][1][2], acc[rt][1][3]));
            float mu2 = fmaxf(fmaxf(acc[rt][2][0], acc[rt][2][1]),
                              fmaxf(acc[rt][2][2], acc[rt][2][3]));
            float mu3 = fmaxf(fmaxf(acc[rt][3][0], acc[rt][3][1]),
                              fmaxf(acc[rt][3][2], acc[rt][3][3]));
            float mloc = fmaxf(fmaxf(mu0, mu1), fmaxf(mu2, mu3));
            // wave-ct row max: reduce across the 4 code sub-groups
            float m = fmaxf(mloc, __shfl_xor(mloc, 16));
            m = fmaxf(m, __shfl_xor(m, 32));
            u32 pme = pmax[rl];
            float pv = dec_f(pme);
            if (m > pv && cgrp == 0) atomicMax(&pmax[rl], enc_f(m));
            float thr = fmaxf(pv, m) - DELTA;
            if (mloc >= thr) {       // rare: exec-masked enumeration
#pragma unroll
                for (int u = 0; u < 4; ++u)
#pragma unroll
                    for (int r = 0; r < 4; ++r) {
                        if (acc[rt][u][r] >= thr) {
                            u32 p = atomicAdd(&cnt[rl], 1u);
                            if (p < CAP) {
                                int code = (w * 64 + ct * 4 + u) * 16 + cgrp * 4 + r;
                                cand[rl * CAP + p] =
                                    ((u32)code << 16) | f2bf(acc[rt][u][r]);
                            }
                        }
                    }
            }
        }
    }
    __syncthreads();   // pmax/cand final: block scanned ALL codes
    if (tid < 64) {
        u32 n = cnt[tid];
        float t2 = dec_f(pmax[tid]) - MARGIN;
        u32 k = 0;
        if (n <= CAP) {
            for (u32 i = 0; i < n; ++i) {
                u32 e = cand[tid * CAP + i];
                float sc = __uint_as_float((e & 0xFFFFu) << 16);
                if (sc >= t2) {
                    if (k < CAPO) cand_g[(size_t)(r0 + tid) * CAPO + k] = (u16)(e >> 16);
                    ++k;
                }
            }
        }
        // k <= n <= CAP == CAPO, so only n>CAP / k==0 can trigger fallback
        cnt_g[r0 + tid] = (n > CAP || k == 0) ? 0xFFFFFFFFu : k;
    }
}

// K4: fp64 rescore of the filtered candidates (typically 2-3, up to CAPO for
// rows whose top scores cluster) + rotation trick + per-block loss partial.
// One wave per row, 4 rows per block. Rotation uses the exact structure of
// this problem: src = x/||x||, tgt = normalized codebook row -> norm_s =
// norm_t = 1, u = s, q = t, eu = 1, scale = 1 (f32 deviations ~1e-7 <<
// tolerance). Chains: ss, then {w2, e.wv} interleaved -> 2 serial times.
__global__ __launch_bounds__(256) void k4_rotate(const float* __restrict__ x,
                                                 const float* __restrict__ cbn,
                                                 const u16* __restrict__ cand_g,
                                                 const u32* __restrict__ cnt_g,
                                                 float* __restrict__ outq,
                                                 float* __restrict__ out_idx,
                                                 float* __restrict__ lossb) {
    __shared__ float xsh[4 * 512];   // per-wave fallback scratch
    __shared__ float lsum[4];
    const int row = blockIdx.x * 4 + (threadIdx.x >> 6);
    const int w = threadIdx.x >> 6;
    const int lane = threadIdx.x & 63;
    const float* xp = x + (size_t)row * DIMV + lane * 8;
    float4 a0 = *(const float4*)xp, a1 = *(const float4*)(xp + 4);
    double xd[8] = {a0.x, a0.y, a0.z, a0.w, a1.x, a1.y, a1.z, a1.w};

    u32 nc = cnt_g[row];
    double best = -1e300;
    int bi = CBSZ;
    if (nc != 0xFFFFFFFFu) {
        u32 i = 0;
        for (; i + 2 <= nc; i += 2) {        // 2-way ILP: interleaved reductions
            int ca = cand_g[(size_t)row * CAPO + i];
            int cb2 = cand_g[(size_t)row * CAPO + i + 1];
            const float* pa = cbn + (size_t)ca * DIMV + lane * 8;
            const float* pb = cbn + (size_t)cb2 * DIMV + lane * 8;
            float4 a0v = *(const float4*)pa, a1v = *(const float4*)(pa + 4);
            float4 b0v = *(const float4*)pb, b1v = *(const float4*)(pb + 4);
            double da = xd[0] * a0v.x + xd[1] * a0v.y + xd[2] * a0v.z + xd[3] * a0v.w
                      + xd[4] * a1v.x + xd[5] * a1v.y + xd[6] * a1v.z + xd[7] * a1v.w;
            double db = xd[0] * b0v.x + xd[1] * b0v.y + xd[2] * b0v.z + xd[3] * b0v.w
                      + xd[4] * b1v.x + xd[5] * b1v.y + xd[6] * b1v.z + xd[7] * b1v.w;
#pragma unroll
            for (int m = 1; m < 64; m <<= 1) {
                da += __shfl_xor(da, m);
                db += __shfl_xor(db, m);
            }
            if (da > best || (da == best && ca < bi)) { best = da; bi = ca; }
            if (db > best || (db == best && cb2 < bi)) { best = db; bi = cb2; }
        }
        if (i < nc) {
            int c = cand_g[(size_t)row * CAPO + i];
            const float* cp = cbn + (size_t)c * DIMV + lane * 8;
            float4 c0 = *(const float4*)cp, c1 = *(const float4*)(cp + 4);
            double d = xd[0] * c0.x + xd[1] * c0.y + xd[2] * c0.z + xd[3] * c0.w
                     + xd[4] * c1.x + xd[5] * c1.y + xd[6] * c1.z + xd[7] * c1.w;
#pragma unroll
            for (int m = 1; m < 64; m <<= 1) d += __shfl_xor(d, m);
            if (d > best || (d == best && c < bi)) { best = d; bi = c; }
        }
    } else {
        // exact parallel fallback (cnt overflow / empty; proven-never here)
        *(float4*)&xsh[w * 512 + lane * 8] = a0;
        *(float4*)&xsh[w * 512 + lane * 8 + 4] = a1;
        float bf = -1e30f;
        for (int c = lane; c < CBSZ; c += 64) {
            const float* cp = cbn + (size_t)c * DIMV;
            float d = 0.f;
            for (int k = 0; k < DIMV; k += 4) {
                d = fmaf(cp[k],     xsh[w * 512 + k],     d);
                d = fmaf(cp[k + 1], xsh[w * 512 + k + 1], d);
                d = fmaf(cp[k + 2], xsh[w * 512 + k + 2], d);
                d = fmaf(cp[k + 3], xsh[w * 512 + k + 3], d);
            }
            bf = fmaxf(bf, d);
        }
        float M = bf;
#pragma unroll
        for (int m = 1; m < 64; m <<= 1) M = fmaxf(M, __shfl_xor(M, m));
        double bd = -1e300;
        int bc = CBSZ;
        for (int c = lane; c < CBSZ; c += 64) {
            const float* cp = cbn + (size_t)c * DIMV;
            float d = 0.f;
            for (int k = 0; k < DIMV; k += 4) {
                d = fmaf(cp[k],     xsh[w * 512 + k],     d);
                d = fmaf(cp[k + 1], xsh[w * 512 + k + 1], d);
                d = fmaf(cp[k + 2], xsh[w * 512 + k + 2], d);
                d = fmaf(cp[k + 3], xsh[w * 512 + k + 3], d);
            }
            if (d >= M - 0.1f) {
                double dd = 0.0;
                for (int k = 0; k < DIMV; ++k)
                    dd += (double)cp[k] * (double)xsh[w * 512 + k];
                if (dd > bd || (dd == bd && c < bc)) { bd = dd; bc = c; }
            }
        }
#pragma unroll
        for (int m = 1; m < 64; m <<= 1) {
            double ov = __shfl_xor(bd, m);
            int oi = __shfl_xor(bc, m);
            if (ov > bd || (ov == bd && oi < bc)) { bd = ov; bc = oi; }
        }
        bi = bc;
    }
    int ci = bi < 0 ? 0 : (bi > CBSZ - 1 ? CBSZ - 1 : bi);

    // --- rotation trick (simplified: unit s, unit t, eu=1, scale=1) ---
    float xf[8] = {a0.x, a0.y, a0.z, a0.w, a1.x, a1.y, a1.z, a1.w};
    float ss = 0.f;
#pragma unroll
    for (int i = 0; i < 8; ++i) ss += xf[i] * xf[i];
    ss = wave_sum(ss);
    float nx = fmaxf(sqrtf(ss), 1e-12f);
    float s[8];
#pragma unroll
    for (int i = 0; i < 8; ++i) s[i] = xf[i] / nx;
    const float* tp = cbn + (size_t)ci * DIMV + lane * 8;
    float4 t0 = *(const float4*)tp, t1 = *(const float4*)(tp + 4);
    float t[8] = {t0.x, t0.y, t0.z, t0.w, t1.x, t1.y, t1.z, t1.w};
    float wv[8];
    float w2 = 0.f, ewr = 0.f, lacc = 0.f;
#pragma unroll
    for (int i = 0; i < 8; ++i) {
        wv[i] = s[i] + t[i];
        w2 += wv[i] * wv[i];
        ewr += s[i] * wv[i];
        float d = s[i] - t[i];
        lacc += d * d;
    }
#pragma unroll
    for (int m = 1; m < 64; m <<= 1) {    // two interleaved chains
        w2 += __shfl_xor(w2, m);
        ewr += __shfl_xor(ewr, m);
    }
    float wn = fmaxf(sqrtf(w2), 1e-12f);
    float iw = 1.f / wn;
    float coef = 2.f * ewr * iw * iw;
    float r[8];
#pragma unroll
    for (int i = 0; i < 8; ++i)
        r[i] = s[i] - coef * wv[i] + 2.f * t[i];
    float* op = outq + (size_t)row * DIMV + lane * 8;
    *(float4*)op = make_float4(r[0], r[1], r[2], r[3]);
    *(float4*)(op + 4) = make_float4(r[4], r[5], r[6], r[7]);
    lacc = wave_sum(lacc);
    if (lane == 0) {
        out_idx[row] = (float)ci;
        lsum[w] = lacc;
    }
    __syncthreads();
    if (threadIdx.x == 0)
        lossb[blockIdx.x] = lsum[0] + lsum[1] + lsum[2] + lsum[3];
}

// K5: reduce 8192 per-block partials deterministically; 1.25 * sum / (B*N*D)
__global__ __launch_bounds__(256) void k5_loss(const float* __restrict__ lossb,
                                               float* __restrict__ outl) {
    __shared__ float wsum[4];
    const int tid = threadIdx.x;
    float s = 0.f;
    for (int i = tid; i < NBLK4; i += 256) s += lossb[i];
    s = wave_sum(s);
    if ((tid & 63) == 0) wsum[tid >> 6] = s;
    __syncthreads();
    if (tid == 0)
        outl[0] = (wsum[0] + wsum[1] + wsum[2] + wsum[3]) * 1.25f / 16777216.0f;
}

extern "C" void kernel_launch(void* const* d_in, const int* in_sizes, int n_in,
                              void* d_out, int out_size, void* d_ws, size_t ws_size,
                              hipStream_t stream) {
    (void)in_sizes; (void)n_in; (void)out_size; (void)ws_size;
    const float* x  = (const float*)d_in[0];   // (8,4096,512) f32
    const float* W  = (const float*)d_in[1];   // (512,512) f32
    const float* cb = (const float*)d_in[2];   // (8192,512) f32
    float* out = (float*)d_out;
    float* out_q = out;                        // 16,777,216 f32
    float* out_i = out + 16777216;             // 32,768 f32
    float* out_l = out + 16777216 + 32768;     // 1 f32

    // xb scratch (fp8, 16MB) lives in the out_q region: written by k0, read
    // by k3, then k4 overwrites out_q with the real output.
    u8* xb = (u8*)d_out;

    float* ws = (float*)d_ws;
    float* cbn = ws;                                  // 4,194,304 f32 (16.8 MB)
    u8*    cbb = (u8*)(cbn + (size_t)CBSZ * DIMV);    // 4,194,304 u8 (4.2 MB)
    u16*   cand_g = (u16*)(cbb + (size_t)CBSZ * DIMV);     // 32768*CAPO u16 (5.2 MB)
    u32*   cnt_g = (u32*)(cand_g + (size_t)MROWS * CAPO);  // 32,768 u32
    float* lossb = (float*)(cnt_g + MROWS);                // 8192 f32

    k0_castx<<<MROWS * DIMV / 8 / 256, 256, 0, stream>>>(x, xb);
    k1_implicit<<<dim3(CBSZ / 64, DIMV / 64), 256, 0, stream>>>(cb, W, cbn);
    k2_normrows<<<CBSZ / 4, 256, 0, stream>>>(cbn, cbb);
    k3_scan<<<MROWS / 64, 512, 0, stream>>>(xb, cbb, cand_g, cnt_g);
    k4_rotate<<<MROWS / 4, 256, 0, stream>>>(x, cbn, cand_g, cnt_g, out_q, out_i, lossb);
    k5_loss<<<1, 256, 0, stream>>>(lossb, out_l);
}